// Round 1
// baseline (570.472 us; speedup 1.0000x reference)
//
#include <hip/hip_runtime.h>
#include <hip/hip_bf16.h>

// MoAGate_240518168735: the reference discards the cdist/argmin result and
// returns (zeros_like, ones_like) of the int cluster_indices array.
// Output = [N zeros (int32), N ones (int32)] concatenated flat.
// Pure-write kernel: 1 MiB total, launch-overhead bound.

__global__ __launch_bounds__(256) void moa_gate_write(int4* __restrict__ out,
                                                      int n_vec4,   // total int4 count = out_size/4
                                                      int half_vec4 // N/4: boundary between zeros and ones
                                                      ) {
    int i = blockIdx.x * blockDim.x + threadIdx.x;
    if (i < n_vec4) {
        int v = (i < half_vec4) ? 0 : 1;
        out[i] = make_int4(v, v, v, v);
    }
}

extern "C" void kernel_launch(void* const* d_in, const int* in_sizes, int n_in,
                              void* d_out, int out_size, void* d_ws, size_t ws_size,
                              hipStream_t stream) {
    (void)d_in; (void)in_sizes; (void)n_in; (void)d_ws; (void)ws_size;

    // out_size = 2*N elements (int32): first N are topk_indices (=0),
    // next N are topk_weights (=1). N = 131072 here; divisible by 4, so
    // int4-vectorized stores never straddle the boundary.
    int n_vec4 = out_size / 4;          // 65536
    int half_vec4 = (out_size / 2) / 4; // 32768

    int threads = 256;
    int blocks = (n_vec4 + threads - 1) / threads;
    moa_gate_write<<<blocks, threads, 0, stream>>>((int4*)d_out, n_vec4, half_vec4);
}